// Round 3
// baseline (636.384 us; speedup 1.0000x reference)
//
#include <hip/hip_runtime.h>
#include <hip/hip_bf16.h>

typedef __bf16 bf16x8 __attribute__((ext_vector_type(8)));
typedef __bf16 bf16x4 __attribute__((ext_vector_type(4)));
typedef float  f32x4  __attribute__((ext_vector_type(4)));

#define LAYERS 16
#define DIM 64
#define NHID 256
#define BATCH 32768
#define MTILE 64
#define NBLOCKS (BATCH / MTILE)   // 512

// packed weight sizes in bf16 elements
#define W0P_PER 16384             // per (net,layer): 16 otiles * 2 ktiles * 512
#define W1P_PER 65536             // 16 otiles * 8 ktiles * 512
#define W2P_PER 16384             // 4 otiles * 8 ktiles * 512
#define W0P_TOT (32 * W0P_PER)    // 524288
#define W1P_TOT (32 * W1P_PER)    // 2097152
#define W2P_TOT (32 * W2P_PER)    // 524288
#define PACK_TOT (W0P_TOT + W1P_TOT + W2P_TOT)  // 3145728 bf16 = 6.29 MB

__device__ __forceinline__ bf16x8 ldw(const __bf16* p) { return *(const bf16x8*)p; }

// ---------------------------------------------------------------------------
// Pack kernel (unchanged): analytic masks, fragment-order output.
// ---------------------------------------------------------------------------
__global__ __launch_bounds__(256) void pack_weights(
    const float* __restrict__ lW0, const float* __restrict__ lW1, const float* __restrict__ lW2,
    const float* __restrict__ sW0, const float* __restrict__ sW1, const float* __restrict__ sW2,
    __bf16* __restrict__ ws)
{
    const long i = ((long)blockIdx.x * 256 + threadIdx.x) * 8;  // elem base
    const float* W; long src; int l, n, k, which;
    if (i < W0P_TOT) {
        int netl = (int)(i / W0P_PER), rem = (int)(i % W0P_PER);
        int net = netl >> 4; l = netl & 15;
        int nt = rem >> 10, kt = (rem >> 9) & 1, lane = (rem >> 3) & 63;
        n = nt * 16 + (lane & 15); k = kt * 32 + (lane >> 4) * 8;
        W = net ? sW0 : lW0; which = 0;
        src = (long)(l * 256 + n) * 64 + k;
    } else if (i < W0P_TOT + W1P_TOT) {
        long r = i - W0P_TOT;
        int netl = (int)(r / W1P_PER), rem = (int)(r % W1P_PER);
        int net = netl >> 4; l = netl & 15;
        int nt = rem >> 12, kt = (rem >> 9) & 7, lane = (rem >> 3) & 63;
        n = nt * 16 + (lane & 15); k = kt * 32 + (lane >> 4) * 8;
        W = net ? sW1 : lW1; which = 1;
        src = (long)(l * 256 + n) * 256 + k;
    } else {
        long r = i - W0P_TOT - W1P_TOT;
        int netl = (int)(r / W2P_PER), rem = (int)(r % W2P_PER);
        int net = netl >> 4; l = netl & 15;
        int nt = rem >> 12, kt = (rem >> 9) & 7, lane = (rem >> 3) & 63;
        n = nt * 16 + (lane & 15); k = kt * 32 + (lane >> 4) * 8;
        W = net ? sW2 : lW2; which = 2;
        src = (long)(l * 64 + n) * 256 + k;
    }
    f32x4 wa = *(const f32x4*)(W + src);
    f32x4 wb = *(const f32x4*)(W + src + 4);
    const int nm = n % 63;                   // mh(n) for which 0/1
    const int pn = (l & 1) ? 63 - n : n;     // perm(n) for which 2 (n < 64 there)
    bf16x8 o;
    #pragma unroll
    for (int j = 0; j < 8; ++j) {
        int kk = k + j;
        bool m;
        if (which == 0)      { int pk = (l & 1) ? 63 - kk : kk; m = (pk <= nm); }
        else if (which == 1) { m = ((kk % 63) <= nm); }
        else                 { m = ((kk % 63) < pn); }
        float v = (j < 4) ? wa[j] : wb[j - 4];
        o[j] = m ? (__bf16)v : (__bf16)0.0f;
    }
    *(bf16x8*)(ws + i) = o;
}

// ---------------------------------------------------------------------------
// Flow kernel, round 10: r9's reuse-4 split with the REGISTER CAP FIXED.
// r9 failed because __launch_bounds__(512,4) behaves as CUDA min-BLOCKS/CU
// on this toolchain (observed VGPR_Count=64 = 512-reg pool / 8 waves/SIMD),
// and reuse-4 needs ~130+ live VGPRs -> catastrophic scratch spill
// (FETCH 33MB -> 459MB, dur 503us). Fix:
//   * __launch_bounds__(512, 2): 2 blocks/CU -> 4 waves/SIMD -> 128-VGPR
//     cap. LDS (72KB) limits us to 2 blocks/CU anyway, so nothing is lost.
//   * wg2a prefetch depth 16 -> 8 frags (kt 0..1; kt 2..7 inline in the
//     G2 MFMA loop) so worst-point live set ~110 < 128, no spill.
// Everything else identical to r9: wave owns 4 otiles x 2 batch-tiles in
// G1/G2 (each activation ds_read_b128 feeds 4 MFMAs), G3 per-(otD,bh),
// in-register coupling, barrier structure B1/B2/B3 per net.
// ---------------------------------------------------------------------------
__global__ void __launch_bounds__(512, 2)
flow_kernel(
    const float* __restrict__ u,
    const __bf16* __restrict__ wp,
    const float* __restrict__ lb0, const float* __restrict__ lb1, const float* __restrict__ lb2,
    const float* __restrict__ sb0, const float* __restrict__ sb1, const float* __restrict__ sb2,
    float* __restrict__ out)
{
    __shared__ __bf16 ybf[4 * 2 * 512];     // [bt][kt(2)][lane][8]   8 KB
    __shared__ __bf16 buf1[4 * 8 * 512];    // [bt][kt(8)][lane][8]  32 KB
    __shared__ __bf16 buf2[4 * 8 * 512];    //                       32 KB

    const int tid  = threadIdx.x;
    const int w    = tid >> 6;        // 0..7
    const int lane = tid & 63;
    const int quad = lane >> 4;
    const int l16  = lane & 15;
    const int blk  = blockIdx.x;

    const int qh = quad >> 1;
    const int qp = (quad & 1) * 4;

    const int otD = w >> 1;           // otile group (G1/G2: otiles 4g..4g+3);
                                      // G3 dim tile; y dim slice
    const int bh  = w & 1;            // batch pair: bt {2bh, 2bh+1}

    const __bf16* w0p = wp;
    const __bf16* w1p = wp + W0P_TOT;
    const __bf16* w2p = wp + W0P_TOT + W1P_TOT;

    // y regs: y[bt][r] = row (blk*64 + bh*32 + bt*16 + l16), dim (otD*16 + quad*4 + r)
    f32x4 y[2];
    #pragma unroll
    for (int bt = 0; bt < 2; ++bt)
        y[bt] = *(const f32x4*)(u + (long)(blk * MTILE + bh * 32 + bt * 16 + l16) * DIM
                                  + otD * 16 + quad * 4);

    // y-staging fragment coords
    const int ktY = w >> 2;
    const int flY = ((((w >> 1) & 1) * 2 + qh) * 16 + l16);

    // prime: G1 weights for (net0, layer0) — wave's otiles are 4*otD + oi
    bf16x8 wg1[8];   // [oi][kt]
    #pragma unroll
    for (int oi = 0; oi < 4; ++oi)
        #pragma unroll
        for (int kt = 0; kt < 2; ++kt)
            wg1[oi * 2 + kt] = ldw(w0p + (long)((4 * otD + oi) * 2 + kt) * 512 + lane * 8);

    for (int l = 0; l < LAYERS; ++l) {
        // stage y -> bf16 B-fragments (one b64 write per bt)
        #pragma unroll
        for (int bt = 0; bt < 2; ++bt) {
            bf16x4 v;
            #pragma unroll
            for (int r = 0; r < 4; ++r) v[r] = (__bf16)y[bt][r];
            *(bf16x4*)&ybf[(((bh * 2 + bt) * 2 + ktY) * 64 + flY) * 8 + qp] = v;
        }
        __syncthreads();  // B1: ybf ready

        f32x4 locr[2], scr[2];

        #pragma unroll
        for (int net = 0; net < 2; ++net) {
            const __bf16* w1b = w1p + (long)(net * 16 + l) * W1P_PER;
            const __bf16* w2b = w2p + (long)(net * 16 + l) * W2P_PER;
            // next G1 slot: net0 -> (net1, l); net1 -> (net0, l+1). l=15/net1
            // lands on slot 16 (net1, l0): in-bounds, values unused.
            const __bf16* w0n = w0p + (long)(net == 0 ? 16 + l : l + 1) * W0P_PER;
            const float* b0 = (net ? sb0 : lb0) + l * 256;
            const float* b1 = (net ? sb1 : lb1) + l * 256;
            const float* b2 = (net ? sb2 : lb2) + l * 64;

            bf16x8 wg2a[8];  // G2 weights kt 0..1 x oi 0..3 (32 VGPR)

            // ---- G1: W0 (A, prefetched in wg1) x y^T (B, fragments) -> h0 frags
            // wave output: otiles {4*otD+oi}, batch tiles {2bh, 2bh+1}
            {
                f32x4 acc[4][2];
                #pragma unroll
                for (int oi = 0; oi < 4; ++oi)
                    #pragma unroll
                    for (int bl = 0; bl < 2; ++bl)
                        acc[oi][bl] = (f32x4){0.f, 0.f, 0.f, 0.f};
                #pragma unroll
                for (int kt = 0; kt < 2; ++kt) {
                    bf16x8 bv[2];
                    #pragma unroll
                    for (int bl = 0; bl < 2; ++bl)
                        bv[bl] = *(const bf16x8*)&ybf[(((2 * bh + bl) * 2 + kt) * 64 + lane) * 8];
                    #pragma unroll
                    for (int oi = 0; oi < 4; ++oi)
                        #pragma unroll
                        for (int bl = 0; bl < 2; ++bl)
                            acc[oi][bl] = __builtin_amdgcn_mfma_f32_16x16x32_bf16(wg1[oi * 2 + kt], bv[bl], acc[oi][bl], 0, 0, 0);
                }
                // prefetch G2 kt=0..1 across the upcoming barrier
                #pragma unroll
                for (int kt = 0; kt < 2; ++kt)
                    #pragma unroll
                    for (int oi = 0; oi < 4; ++oi)
                        wg2a[kt * 4 + oi] = ldw(w1b + (long)((4 * otD + oi) * 8 + kt) * 512 + lane * 8);
                // epilogue: relu + bias -> buf1 fragments
                // hidden h = O*16 + quad*4 + r (O = 4*otD+oi) -> kt1 = O>>1,
                // frag-lane = l16 + 16*((O&1)*2+qh), j = qp + r
                #pragma unroll
                for (int oi = 0; oi < 4; ++oi) {
                    const int O = 4 * otD + oi;
                    f32x4 bias = *(const f32x4*)(b0 + O * 16 + quad * 4);
                    const int kt1 = O >> 1;
                    const int fl  = ((O & 1) * 2 + qh) * 16 + l16;
                    #pragma unroll
                    for (int bl = 0; bl < 2; ++bl) {
                        bf16x4 v;
                        #pragma unroll
                        for (int r = 0; r < 4; ++r)
                            v[r] = (__bf16)fmaxf(acc[oi][bl][r] + bias[r], 0.f);
                        *(bf16x4*)&buf1[(((2 * bh + bl) * 8 + kt1) * 64 + fl) * 8 + qp] = v;
                    }
                }
            }
            __syncthreads();  // B2: h0 ready

            bf16x8 wg3[8];    // G3 weights [kt]

            // ---- G2: W1 (A, kt<2 prefetched) x h0 (B, fragments) -> h1 frags
            {
                f32x4 acc[4][2];
                #pragma unroll
                for (int oi = 0; oi < 4; ++oi)
                    #pragma unroll
                    for (int bl = 0; bl < 2; ++bl)
                        acc[oi][bl] = (f32x4){0.f, 0.f, 0.f, 0.f};
                #pragma unroll
                for (int kt = 0; kt < 8; ++kt) {
                    bf16x8 aw[4];
                    #pragma unroll
                    for (int oi = 0; oi < 4; ++oi)
                        aw[oi] = (kt < 2) ? wg2a[kt * 4 + oi]
                                          : ldw(w1b + (long)((4 * otD + oi) * 8 + kt) * 512 + lane * 8);
                    bf16x8 bv[2];
                    #pragma unroll
                    for (int bl = 0; bl < 2; ++bl)
                        bv[bl] = *(const bf16x8*)&buf1[(((2 * bh + bl) * 8 + kt) * 64 + lane) * 8];
                    #pragma unroll
                    for (int oi = 0; oi < 4; ++oi)
                        #pragma unroll
                        for (int bl = 0; bl < 2; ++bl)
                            acc[oi][bl] = __builtin_amdgcn_mfma_f32_16x16x32_bf16(aw[oi], bv[bl], acc[oi][bl], 0, 0, 0);
                }
                // epilogue: relu + bias -> buf2 fragments
                #pragma unroll
                for (int oi = 0; oi < 4; ++oi) {
                    const int O = 4 * otD + oi;
                    f32x4 bias = *(const f32x4*)(b1 + O * 16 + quad * 4);
                    const int kt1 = O >> 1;
                    const int fl  = ((O & 1) * 2 + qh) * 16 + l16;
                    #pragma unroll
                    for (int bl = 0; bl < 2; ++bl) {
                        bf16x4 v;
                        #pragma unroll
                        for (int r = 0; r < 4; ++r)
                            v[r] = (__bf16)fmaxf(acc[oi][bl][r] + bias[r], 0.f);
                        *(bf16x4*)&buf2[(((2 * bh + bl) * 8 + kt1) * 64 + fl) * 8 + qp] = v;
                    }
                }
                // prefetch G3 weights across the upcoming barrier (wave pair
                // w, w^1 load the same otD tile — 2x W2 loads, negligible)
                #pragma unroll
                for (int kt = 0; kt < 8; ++kt)
                    wg3[kt] = ldw(w2b + (long)(otD * 8 + kt) * 512 + lane * 8);
            }
            __syncthreads();  // B3: h1 ready (also all buf1 reads done)

            // ---- G3: W2 (A, prefetched in wg3) x h1 (B, fragments) -> regs
            // wave owns (dim tile otD, batch half bh): bt in {2bh, 2bh+1}
            {
                f32x4 acc3[2];
                #pragma unroll
                for (int bt = 0; bt < 2; ++bt)
                    acc3[bt] = (f32x4){0.f, 0.f, 0.f, 0.f};
                #pragma unroll
                for (int kt = 0; kt < 8; ++kt) {
                    #pragma unroll
                    for (int bt = 0; bt < 2; ++bt) {
                        bf16x8 bv = *(const bf16x8*)&buf2[(((bh * 2 + bt) * 8 + kt) * 64 + lane) * 8];
                        acc3[bt] = __builtin_amdgcn_mfma_f32_16x16x32_bf16(wg3[kt], bv, acc3[bt], 0, 0, 0);
                    }
                }
                // prefetch next G1 weights (low-pressure region)
                #pragma unroll
                for (int oi = 0; oi < 4; ++oi)
                    #pragma unroll
                    for (int kt = 0; kt < 2; ++kt)
                        wg1[oi * 2 + kt] = ldw(w0n + (long)((4 * otD + oi) * 2 + kt) * 512 + lane * 8);
                f32x4 bias = *(const f32x4*)(b2 + otD * 16 + quad * 4);
                if (net == 0) {
                    #pragma unroll
                    for (int bt = 0; bt < 2; ++bt)
                        #pragma unroll
                        for (int r = 0; r < 4; ++r)
                            locr[bt][r] = acc3[bt][r] + bias[r];
                } else {
                    #pragma unroll
                    for (int bt = 0; bt < 2; ++bt)
                        #pragma unroll
                        for (int r = 0; r < 4; ++r)
                            scr[bt][r] = acc3[bt][r] + bias[r];
                }
            }
            // no barrier after G3: next G1 writes buf1 (reads drained at B3);
            // next G2's buf2 writes are behind the next B2
        }

        // coupling update, pure registers: y = exp(-sc) * (y - loc)
        #pragma unroll
        for (int bt = 0; bt < 2; ++bt)
            #pragma unroll
            for (int r = 0; r < 4; ++r)
                y[bt][r] = __expf(-scr[bt][r]) * (y[bt][r] - locr[bt][r]);
        // next ybf write safe: all ybf readers (both nets' G1) are behind this
        // layer's B2 barriers
    }

    #pragma unroll
    for (int bt = 0; bt < 2; ++bt)
        *(f32x4*)(out + (long)(blk * MTILE + bh * 32 + bt * 16 + l16) * DIM
                      + otD * 16 + quad * 4) = y[bt];
}

extern "C" void kernel_launch(void* const* d_in, const int* in_sizes, int n_in,
                              void* d_out, int out_size, void* d_ws, size_t ws_size,
                              hipStream_t stream) {
    const float* u   = (const float*)d_in[0];
    const float* lW0 = (const float*)d_in[1];
    const float* lb0 = (const float*)d_in[2];
    const float* lW1 = (const float*)d_in[3];
    const float* lb1 = (const float*)d_in[4];
    const float* lW2 = (const float*)d_in[5];
    const float* lb2 = (const float*)d_in[6];
    const float* sW0 = (const float*)d_in[7];
    const float* sb0 = (const float*)d_in[8];
    const float* sW1 = (const float*)d_in[9];
    const float* sb1 = (const float*)d_in[10];
    const float* sW2 = (const float*)d_in[11];
    const float* sb2 = (const float*)d_in[12];
    // d_in[13..15] = M0,M1,M2 — masks are computed analytically in pack_weights

    if (ws_size < (size_t)PACK_TOT * sizeof(__bf16)) return;
    __bf16* ws = (__bf16*)d_ws;

    pack_weights<<<PACK_TOT / 8 / 256, 256, 0, stream>>>(
        lW0, lW1, lW2, sW0, sW1, sW2, ws);
    flow_kernel<<<NBLOCKS, 512, 0, stream>>>(
        u, ws, lb0, lb1, lb2, sb0, sb1, sb2, (float*)d_out);
}

// Round 4
// 330.241 us; speedup vs baseline: 1.9270x; 1.9270x over previous
//
#include <hip/hip_runtime.h>
#include <hip/hip_bf16.h>

typedef __bf16 bf16x8 __attribute__((ext_vector_type(8)));
typedef __bf16 bf16x4 __attribute__((ext_vector_type(4)));
typedef float  f32x4  __attribute__((ext_vector_type(4)));

#define LAYERS 16
#define DIM 64
#define NHID 256
#define BATCH 32768
#define MTILE 64
#define NBLOCKS (BATCH / MTILE)   // 512

// packed weight sizes in bf16 elements
#define W0P_PER 16384             // per (net,layer): 16 otiles * 2 ktiles * 512
#define W1P_PER 65536             // 16 otiles * 8 ktiles * 512
#define W2P_PER 16384             // 4 otiles * 8 ktiles * 512
#define W0P_TOT (32 * W0P_PER)    // 524288
#define W1P_TOT (32 * W1P_PER)    // 2097152
#define W2P_TOT (32 * W2P_PER)    // 524288
#define PACK_TOT (W0P_TOT + W1P_TOT + W2P_TOT)  // 3145728 bf16 = 6.29 MB

__device__ __forceinline__ bf16x8 ldw(const __bf16* p) { return *(const bf16x8*)p; }

// ---------------------------------------------------------------------------
// Pack kernel (unchanged): analytic masks, fragment-order output.
// ---------------------------------------------------------------------------
__global__ __launch_bounds__(256) void pack_weights(
    const float* __restrict__ lW0, const float* __restrict__ lW1, const float* __restrict__ lW2,
    const float* __restrict__ sW0, const float* __restrict__ sW1, const float* __restrict__ sW2,
    __bf16* __restrict__ ws)
{
    const long i = ((long)blockIdx.x * 256 + threadIdx.x) * 8;  // elem base
    const float* W; long src; int l, n, k, which;
    if (i < W0P_TOT) {
        int netl = (int)(i / W0P_PER), rem = (int)(i % W0P_PER);
        int net = netl >> 4; l = netl & 15;
        int nt = rem >> 10, kt = (rem >> 9) & 1, lane = (rem >> 3) & 63;
        n = nt * 16 + (lane & 15); k = kt * 32 + (lane >> 4) * 8;
        W = net ? sW0 : lW0; which = 0;
        src = (long)(l * 256 + n) * 64 + k;
    } else if (i < W0P_TOT + W1P_TOT) {
        long r = i - W0P_TOT;
        int netl = (int)(r / W1P_PER), rem = (int)(r % W1P_PER);
        int net = netl >> 4; l = netl & 15;
        int nt = rem >> 12, kt = (rem >> 9) & 7, lane = (rem >> 3) & 63;
        n = nt * 16 + (lane & 15); k = kt * 32 + (lane >> 4) * 8;
        W = net ? sW1 : lW1; which = 1;
        src = (long)(l * 256 + n) * 256 + k;
    } else {
        long r = i - W0P_TOT - W1P_TOT;
        int netl = (int)(r / W2P_PER), rem = (int)(r % W2P_PER);
        int net = netl >> 4; l = netl & 15;
        int nt = rem >> 12, kt = (rem >> 9) & 7, lane = (rem >> 3) & 63;
        n = nt * 16 + (lane & 15); k = kt * 32 + (lane >> 4) * 8;
        W = net ? sW2 : lW2; which = 2;
        src = (long)(l * 64 + n) * 256 + k;
    }
    f32x4 wa = *(const f32x4*)(W + src);
    f32x4 wb = *(const f32x4*)(W + src + 4);
    const int nm = n % 63;                   // mh(n) for which 0/1
    const int pn = (l & 1) ? 63 - n : n;     // perm(n) for which 2 (n < 64 there)
    bf16x8 o;
    #pragma unroll
    for (int j = 0; j < 8; ++j) {
        int kk = k + j;
        bool m;
        if (which == 0)      { int pk = (l & 1) ? 63 - kk : kk; m = (pk <= nm); }
        else if (which == 1) { m = ((kk % 63) <= nm); }
        else                 { m = ((kk % 63) < pn); }
        float v = (j < 4) ? wa[j] : wb[j - 4];
        o[j] = m ? (__bf16)v : (__bf16)0.0f;
    }
    *(bf16x8*)(ws + i) = o;
}

// ---------------------------------------------------------------------------
// Flow kernel, round 11: r8 champion structure (reuse-2 split, deep weight
// prefetch: wg2a covers G2 kt0..3, wg3 covers all of G3, wg1 covers next G1 —
// every global weight load is issued >=1 barrier-phase before consumption)
// with ONE change: __launch_bounds__(512, 2) instead of (512, 4).
// Evidence from r8/r9/r10: the 2nd arg acts as min-BLOCKS/CU on this
// toolchain ((512,4) -> VGPR cap 64, (512,2) -> cap 128). r8's cap-64 forced
// a mild scratch spill (WRITE 17.4MB vs 8.2 ideal, FETCH +5MB). Cap 128
// lets the ~100-reg demand allocate honestly. LDS (72KB -> 2 blocks/CU)
// still sets residency: 4 waves/SIMD x ~100 VGPR = 400 <= 512, occupancy
// unchanged. r10's regression was the shallow prefetch (inline G2 loads
// serialized on L2 latency), NOT the launch-bounds change — reverted here.
// ---------------------------------------------------------------------------
__global__ void __launch_bounds__(512, 2)
flow_kernel(
    const float* __restrict__ u,
    const __bf16* __restrict__ wp,
    const float* __restrict__ lb0, const float* __restrict__ lb1, const float* __restrict__ lb2,
    const float* __restrict__ sb0, const float* __restrict__ sb1, const float* __restrict__ sb2,
    float* __restrict__ out)
{
    __shared__ __bf16 ybf[4 * 2 * 512];     // [bt][kt(2)][lane][8]   8 KB
    __shared__ __bf16 buf1[4 * 8 * 512];    // [bt][kt(8)][lane][8]  32 KB
    __shared__ __bf16 buf2[4 * 8 * 512];    //                       32 KB

    const int tid  = threadIdx.x;
    const int w    = tid >> 6;        // 0..7
    const int lane = tid & 63;
    const int quad = lane >> 4;
    const int l16  = lane & 15;
    const int blk  = blockIdx.x;

    const int qh = quad >> 1;
    const int qp = (quad & 1) * 4;

    const int otD = w >> 1;           // G3 dim tile (0..3); y dim slice
    const int bh  = w & 1;            // G3 batch half; y batch half

    const __bf16* w0p = wp;
    const __bf16* w1p = wp + W0P_TOT;
    const __bf16* w2p = wp + W0P_TOT + W1P_TOT;

    // y regs: y[bt][r] = row (blk*64 + bh*32 + bt*16 + l16), dim (otD*16 + quad*4 + r)
    f32x4 y[2];
    #pragma unroll
    for (int bt = 0; bt < 2; ++bt)
        y[bt] = *(const f32x4*)(u + (long)(blk * MTILE + bh * 32 + bt * 16 + l16) * DIM
                                  + otD * 16 + quad * 4);

    // y-staging fragment coords: dim D = otD*16 + quad*4 + r ->
    // ktY = D/32 = w>>2, frag-lane = l16 + 16*(((w>>1)&1)*2 + qh), j = qp + r
    const int ktY = w >> 2;
    const int flY = ((((w >> 1) & 1) * 2 + qh) * 16 + l16);

    // prime: G1 weights for (net0, layer0) — wave's otiles are {2w, 2w+1}
    bf16x8 wg1[4];   // [oi][kt]
    #pragma unroll
    for (int oi = 0; oi < 2; ++oi)
        #pragma unroll
        for (int kt = 0; kt < 2; ++kt)
            wg1[oi * 2 + kt] = ldw(w0p + (long)((2 * w + oi) * 2 + kt) * 512 + lane * 8);

    for (int l = 0; l < LAYERS; ++l) {
        // stage y -> bf16 B-fragments (one b64 write per bt)
        #pragma unroll
        for (int bt = 0; bt < 2; ++bt) {
            bf16x4 v;
            #pragma unroll
            for (int r = 0; r < 4; ++r) v[r] = (__bf16)y[bt][r];
            *(bf16x4*)&ybf[(((bh * 2 + bt) * 2 + ktY) * 64 + flY) * 8 + qp] = v;
        }
        __syncthreads();  // B1: ybf ready

        f32x4 locr[2], scr[2];

        #pragma unroll
        for (int net = 0; net < 2; ++net) {
            const __bf16* w1b = w1p + (long)(net * 16 + l) * W1P_PER;
            const __bf16* w2b = w2p + (long)(net * 16 + l) * W2P_PER;
            // next G1 slot: net0 -> (net1, l); net1 -> (net0, l+1). l=15/net1
            // lands on slot 16 (net1, l0): in-bounds, values unused.
            const __bf16* w0n = w0p + (long)(net == 0 ? 16 + l : l + 1) * W0P_PER;
            const float* b0 = (net ? sb0 : lb0) + l * 256;
            const float* b1 = (net ? sb1 : lb1) + l * 256;
            const float* b2 = (net ? sb2 : lb2) + l * 64;

            bf16x8 wg2a[8];  // G2 weights kt 0..3 x oi 0..1

            // ---- G1: W0 (A, prefetched in wg1) x y^T (B, fragments) -> h0 frags
            {
                f32x4 acc[2][4];
                #pragma unroll
                for (int oi = 0; oi < 2; ++oi)
                    #pragma unroll
                    for (int bt = 0; bt < 4; ++bt)
                        acc[oi][bt] = (f32x4){0.f, 0.f, 0.f, 0.f};
                #pragma unroll
                for (int kt = 0; kt < 2; ++kt) {
                    bf16x8 bv[4];
                    #pragma unroll
                    for (int bt = 0; bt < 4; ++bt)
                        bv[bt] = *(const bf16x8*)&ybf[((bt * 2 + kt) * 64 + lane) * 8];
                    #pragma unroll
                    for (int oi = 0; oi < 2; ++oi)
                        #pragma unroll
                        for (int bt = 0; bt < 4; ++bt)
                            acc[oi][bt] = __builtin_amdgcn_mfma_f32_16x16x32_bf16(wg1[oi * 2 + kt], bv[bt], acc[oi][bt], 0, 0, 0);
                }
                // prefetch G2 kt=0..3 across the upcoming barrier
                #pragma unroll
                for (int kt = 0; kt < 4; ++kt)
                    #pragma unroll
                    for (int oi = 0; oi < 2; ++oi)
                        wg2a[kt * 2 + oi] = ldw(w1b + (long)((2 * w + oi) * 8 + kt) * 512 + lane * 8);
                // epilogue: relu + bias -> buf1 fragments
                // hidden h = (2w+oi)*16 + quad*4 + r -> kt1 = h/32 = w,
                // frag-lane = l16 + 16*(oi*2+qh), j = qp + r
                #pragma unroll
                for (int oi = 0; oi < 2; ++oi) {
                    f32x4 bias = *(const f32x4*)(b0 + (2 * w + oi) * 16 + quad * 4);
                    const int fl = ((oi * 2 + qh) * 16 + l16);
                    #pragma unroll
                    for (int bt = 0; bt < 4; ++bt) {
                        bf16x4 v;
                        #pragma unroll
                        for (int r = 0; r < 4; ++r)
                            v[r] = (__bf16)fmaxf(acc[oi][bt][r] + bias[r], 0.f);
                        *(bf16x4*)&buf1[((bt * 8 + w) * 64 + fl) * 8 + qp] = v;
                    }
                }
            }
            __syncthreads();  // B2: h0 ready

            bf16x8 wg3[8];    // G3 weights [kt]

            // ---- G2: W1 (A, kt<4 prefetched) x h0 (B, fragments) -> h1 frags
            {
                f32x4 acc[2][4];
                #pragma unroll
                for (int oi = 0; oi < 2; ++oi)
                    #pragma unroll
                    for (int bt = 0; bt < 4; ++bt)
                        acc[oi][bt] = (f32x4){0.f, 0.f, 0.f, 0.f};
                #pragma unroll
                for (int kt = 0; kt < 8; ++kt) {
                    bf16x8 aw[2];
                    #pragma unroll
                    for (int oi = 0; oi < 2; ++oi)
                        aw[oi] = (kt < 4) ? wg2a[kt * 2 + oi]
                                          : ldw(w1b + (long)((2 * w + oi) * 8 + kt) * 512 + lane * 8);
                    bf16x8 bv[4];
                    #pragma unroll
                    for (int bt = 0; bt < 4; ++bt)
                        bv[bt] = *(const bf16x8*)&buf1[((bt * 8 + kt) * 64 + lane) * 8];
                    #pragma unroll
                    for (int oi = 0; oi < 2; ++oi)
                        #pragma unroll
                        for (int bt = 0; bt < 4; ++bt)
                            acc[oi][bt] = __builtin_amdgcn_mfma_f32_16x16x32_bf16(aw[oi], bv[bt], acc[oi][bt], 0, 0, 0);
                }
                // epilogue: relu + bias -> buf2 fragments
                #pragma unroll
                for (int oi = 0; oi < 2; ++oi) {
                    f32x4 bias = *(const f32x4*)(b1 + (2 * w + oi) * 16 + quad * 4);
                    const int fl = ((oi * 2 + qh) * 16 + l16);
                    #pragma unroll
                    for (int bt = 0; bt < 4; ++bt) {
                        bf16x4 v;
                        #pragma unroll
                        for (int r = 0; r < 4; ++r)
                            v[r] = (__bf16)fmaxf(acc[oi][bt][r] + bias[r], 0.f);
                        *(bf16x4*)&buf2[((bt * 8 + w) * 64 + fl) * 8 + qp] = v;
                    }
                }
                // prefetch G3 weights across the upcoming barrier (wave pair
                // w, w^1 load the same otD tile — 2x W2 loads, negligible)
                #pragma unroll
                for (int kt = 0; kt < 8; ++kt)
                    wg3[kt] = ldw(w2b + (long)(otD * 8 + kt) * 512 + lane * 8);
            }
            __syncthreads();  // B3: h1 ready (also all buf1 reads done)

            // ---- G3: W2 (A, prefetched in wg3) x h1 (B, fragments) -> regs
            // wave owns (dim tile otD, batch half bh): bt in {bh*2, bh*2+1}
            {
                f32x4 acc3[2];
                #pragma unroll
                for (int bt = 0; bt < 2; ++bt)
                    acc3[bt] = (f32x4){0.f, 0.f, 0.f, 0.f};
                #pragma unroll
                for (int kt = 0; kt < 8; ++kt) {
                    #pragma unroll
                    for (int bt = 0; bt < 2; ++bt) {
                        bf16x8 bv = *(const bf16x8*)&buf2[(((bh * 2 + bt) * 8 + kt) * 64 + lane) * 8];
                        acc3[bt] = __builtin_amdgcn_mfma_f32_16x16x32_bf16(wg3[kt], bv, acc3[bt], 0, 0, 0);
                    }
                }
                // prefetch next G1 weights (low-pressure region)
                #pragma unroll
                for (int oi = 0; oi < 2; ++oi)
                    #pragma unroll
                    for (int kt = 0; kt < 2; ++kt)
                        wg1[oi * 2 + kt] = ldw(w0n + (long)((2 * w + oi) * 2 + kt) * 512 + lane * 8);
                f32x4 bias = *(const f32x4*)(b2 + otD * 16 + quad * 4);
                if (net == 0) {
                    #pragma unroll
                    for (int bt = 0; bt < 2; ++bt)
                        #pragma unroll
                        for (int r = 0; r < 4; ++r)
                            locr[bt][r] = acc3[bt][r] + bias[r];
                } else {
                    #pragma unroll
                    for (int bt = 0; bt < 2; ++bt)
                        #pragma unroll
                        for (int r = 0; r < 4; ++r)
                            scr[bt][r] = acc3[bt][r] + bias[r];
                }
            }
            // no barrier after G3: next G1 writes buf1 (reads drained at B3);
            // next G2's buf2 writes are behind the next B2
        }

        // coupling update, pure registers: y = exp(-sc) * (y - loc)
        #pragma unroll
        for (int bt = 0; bt < 2; ++bt)
            #pragma unroll
            for (int r = 0; r < 4; ++r)
                y[bt][r] = __expf(-scr[bt][r]) * (y[bt][r] - locr[bt][r]);
        // next ybf write safe: all ybf readers (both nets' G1) are behind this
        // layer's B2 barriers
    }

    #pragma unroll
    for (int bt = 0; bt < 2; ++bt)
        *(f32x4*)(out + (long)(blk * MTILE + bh * 32 + bt * 16 + l16) * DIM
                      + otD * 16 + quad * 4) = y[bt];
}

extern "C" void kernel_launch(void* const* d_in, const int* in_sizes, int n_in,
                              void* d_out, int out_size, void* d_ws, size_t ws_size,
                              hipStream_t stream) {
    const float* u   = (const float*)d_in[0];
    const float* lW0 = (const float*)d_in[1];
    const float* lb0 = (const float*)d_in[2];
    const float* lW1 = (const float*)d_in[3];
    const float* lb1 = (const float*)d_in[4];
    const float* lW2 = (const float*)d_in[5];
    const float* lb2 = (const float*)d_in[6];
    const float* sW0 = (const float*)d_in[7];
    const float* sb0 = (const float*)d_in[8];
    const float* sW1 = (const float*)d_in[9];
    const float* sb1 = (const float*)d_in[10];
    const float* sW2 = (const float*)d_in[11];
    const float* sb2 = (const float*)d_in[12];
    // d_in[13..15] = M0,M1,M2 — masks are computed analytically in pack_weights

    if (ws_size < (size_t)PACK_TOT * sizeof(__bf16)) return;
    __bf16* ws = (__bf16*)d_ws;

    pack_weights<<<PACK_TOT / 8 / 256, 256, 0, stream>>>(
        lW0, lW1, lW2, sW0, sW1, sW2, ws);
    flow_kernel<<<NBLOCKS, 512, 0, stream>>>(
        u, ws, lb0, lb1, lb2, sb0, sb1, sb2, (float*)d_out);
}

// Round 5
// 298.122 us; speedup vs baseline: 2.1346x; 1.1077x over previous
//
#include <hip/hip_runtime.h>
#include <hip/hip_bf16.h>

typedef __bf16 bf16x8 __attribute__((ext_vector_type(8)));
typedef __bf16 bf16x4 __attribute__((ext_vector_type(4)));
typedef float  f32x4  __attribute__((ext_vector_type(4)));

#define LAYERS 16
#define DIM 64
#define NHID 256
#define BATCH 32768
#define MTILE 64
#define NBLOCKS (BATCH / MTILE)   // 512

// packed weight sizes in bf16 elements
#define W0P_PER 16384             // per (net,layer): 16 otiles * 2 ktiles * 512
#define W1P_PER 65536             // 16 otiles * 8 ktiles * 512
#define W2P_PER 16384             // 4 otiles * 8 ktiles * 512
#define W0P_TOT (32 * W0P_PER)    // 524288
#define W1P_TOT (32 * W1P_PER)    // 2097152
#define W2P_TOT (32 * W2P_PER)    // 524288
#define PACK_TOT (W0P_TOT + W1P_TOT + W2P_TOT)  // 3145728 bf16 = 6.29 MB

__device__ __forceinline__ bf16x8 ldw(const __bf16* p) { return *(const bf16x8*)p; }

// ---------------------------------------------------------------------------
// Pack kernel (unchanged): analytic masks, fragment-order output.
// ---------------------------------------------------------------------------
__global__ __launch_bounds__(256) void pack_weights(
    const float* __restrict__ lW0, const float* __restrict__ lW1, const float* __restrict__ lW2,
    const float* __restrict__ sW0, const float* __restrict__ sW1, const float* __restrict__ sW2,
    __bf16* __restrict__ ws)
{
    const long i = ((long)blockIdx.x * 256 + threadIdx.x) * 8;  // elem base
    const float* W; long src; int l, n, k, which;
    if (i < W0P_TOT) {
        int netl = (int)(i / W0P_PER), rem = (int)(i % W0P_PER);
        int net = netl >> 4; l = netl & 15;
        int nt = rem >> 10, kt = (rem >> 9) & 1, lane = (rem >> 3) & 63;
        n = nt * 16 + (lane & 15); k = kt * 32 + (lane >> 4) * 8;
        W = net ? sW0 : lW0; which = 0;
        src = (long)(l * 256 + n) * 64 + k;
    } else if (i < W0P_TOT + W1P_TOT) {
        long r = i - W0P_TOT;
        int netl = (int)(r / W1P_PER), rem = (int)(r % W1P_PER);
        int net = netl >> 4; l = netl & 15;
        int nt = rem >> 12, kt = (rem >> 9) & 7, lane = (rem >> 3) & 63;
        n = nt * 16 + (lane & 15); k = kt * 32 + (lane >> 4) * 8;
        W = net ? sW1 : lW1; which = 1;
        src = (long)(l * 256 + n) * 256 + k;
    } else {
        long r = i - W0P_TOT - W1P_TOT;
        int netl = (int)(r / W2P_PER), rem = (int)(r % W2P_PER);
        int net = netl >> 4; l = netl & 15;
        int nt = rem >> 12, kt = (rem >> 9) & 7, lane = (rem >> 3) & 63;
        n = nt * 16 + (lane & 15); k = kt * 32 + (lane >> 4) * 8;
        W = net ? sW2 : lW2; which = 2;
        src = (long)(l * 64 + n) * 256 + k;
    }
    f32x4 wa = *(const f32x4*)(W + src);
    f32x4 wb = *(const f32x4*)(W + src + 4);
    const int nm = n % 63;                   // mh(n) for which 0/1
    const int pn = (l & 1) ? 63 - n : n;     // perm(n) for which 2 (n < 64 there)
    bf16x8 o;
    #pragma unroll
    for (int j = 0; j < 8; ++j) {
        int kk = k + j;
        bool m;
        if (which == 0)      { int pk = (l & 1) ? 63 - kk : kk; m = (pk <= nm); }
        else if (which == 1) { m = ((kk % 63) <= nm); }
        else                 { m = ((kk % 63) < pn); }
        float v = (j < 4) ? wa[j] : wb[j - 4];
        o[j] = m ? (__bf16)v : (__bf16)0.0f;
    }
    *(bf16x8*)(ws + i) = o;
}

// ---------------------------------------------------------------------------
// Flow kernel, round 12: r11 structure (reuse-2 split, deep weight prefetch)
// with the REGISTER/RESIDENCY KNOB FIXED PROPERLY.
// Evidence ledger:
//   (512,4): arch-VGPR cap 64 (CUDA min-blocks semantics: 4blk*8w/4SIMD =
//            8 w/EU -> 512/8 = 64), 2 blocks/CU resident, mild spill, 234us.
//   (512,2): cap 128, arch VGPR 80, NO spill — but only 1 block/CU resident
//            (occupancy 23%). Explanation: MFMA accumulators live in AGPRs
//            (CSV VGPR_Count shows arch only); unconstrained, arch+acc
//            total > 128/wave -> only 3 waves/SIMD fit -> 1 block of 8 waves.
// Fix: explicit amdgpu_waves_per_eu(4) — the allocator must fit TOTAL
// (arch+acc) regs in 512/4 = 128, giving 4 waves/SIMD = 2 blocks/CU, and
// the ~110-reg demand fits 128 without spill. flat_work_group_size pinned
// to exactly 512. Everything else byte-identical to r11.
// ---------------------------------------------------------------------------
__global__ void __attribute__((amdgpu_flat_work_group_size(512, 512)))
                __attribute__((amdgpu_waves_per_eu(4)))
flow_kernel(
    const float* __restrict__ u,
    const __bf16* __restrict__ wp,
    const float* __restrict__ lb0, const float* __restrict__ lb1, const float* __restrict__ lb2,
    const float* __restrict__ sb0, const float* __restrict__ sb1, const float* __restrict__ sb2,
    float* __restrict__ out)
{
    __shared__ __bf16 ybf[4 * 2 * 512];     // [bt][kt(2)][lane][8]   8 KB
    __shared__ __bf16 buf1[4 * 8 * 512];    // [bt][kt(8)][lane][8]  32 KB
    __shared__ __bf16 buf2[4 * 8 * 512];    //                       32 KB

    const int tid  = threadIdx.x;
    const int w    = tid >> 6;        // 0..7
    const int lane = tid & 63;
    const int quad = lane >> 4;
    const int l16  = lane & 15;
    const int blk  = blockIdx.x;

    const int qh = quad >> 1;
    const int qp = (quad & 1) * 4;

    const int otD = w >> 1;           // G3 dim tile (0..3); y dim slice
    const int bh  = w & 1;            // G3 batch half; y batch half

    const __bf16* w0p = wp;
    const __bf16* w1p = wp + W0P_TOT;
    const __bf16* w2p = wp + W0P_TOT + W1P_TOT;

    // y regs: y[bt][r] = row (blk*64 + bh*32 + bt*16 + l16), dim (otD*16 + quad*4 + r)
    f32x4 y[2];
    #pragma unroll
    for (int bt = 0; bt < 2; ++bt)
        y[bt] = *(const f32x4*)(u + (long)(blk * MTILE + bh * 32 + bt * 16 + l16) * DIM
                                  + otD * 16 + quad * 4);

    // y-staging fragment coords: dim D = otD*16 + quad*4 + r ->
    // ktY = D/32 = w>>2, frag-lane = l16 + 16*(((w>>1)&1)*2 + qh), j = qp + r
    const int ktY = w >> 2;
    const int flY = ((((w >> 1) & 1) * 2 + qh) * 16 + l16);

    // prime: G1 weights for (net0, layer0) — wave's otiles are {2w, 2w+1}
    bf16x8 wg1[4];   // [oi][kt]
    #pragma unroll
    for (int oi = 0; oi < 2; ++oi)
        #pragma unroll
        for (int kt = 0; kt < 2; ++kt)
            wg1[oi * 2 + kt] = ldw(w0p + (long)((2 * w + oi) * 2 + kt) * 512 + lane * 8);

    for (int l = 0; l < LAYERS; ++l) {
        // stage y -> bf16 B-fragments (one b64 write per bt)
        #pragma unroll
        for (int bt = 0; bt < 2; ++bt) {
            bf16x4 v;
            #pragma unroll
            for (int r = 0; r < 4; ++r) v[r] = (__bf16)y[bt][r];
            *(bf16x4*)&ybf[(((bh * 2 + bt) * 2 + ktY) * 64 + flY) * 8 + qp] = v;
        }
        __syncthreads();  // B1: ybf ready

        f32x4 locr[2], scr[2];

        #pragma unroll
        for (int net = 0; net < 2; ++net) {
            const __bf16* w1b = w1p + (long)(net * 16 + l) * W1P_PER;
            const __bf16* w2b = w2p + (long)(net * 16 + l) * W2P_PER;
            // next G1 slot: net0 -> (net1, l); net1 -> (net0, l+1). l=15/net1
            // lands on slot 16 (net1, l0): in-bounds, values unused.
            const __bf16* w0n = w0p + (long)(net == 0 ? 16 + l : l + 1) * W0P_PER;
            const float* b0 = (net ? sb0 : lb0) + l * 256;
            const float* b1 = (net ? sb1 : lb1) + l * 256;
            const float* b2 = (net ? sb2 : lb2) + l * 64;

            bf16x8 wg2a[8];  // G2 weights kt 0..3 x oi 0..1

            // ---- G1: W0 (A, prefetched in wg1) x y^T (B, fragments) -> h0 frags
            {
                f32x4 acc[2][4];
                #pragma unroll
                for (int oi = 0; oi < 2; ++oi)
                    #pragma unroll
                    for (int bt = 0; bt < 4; ++bt)
                        acc[oi][bt] = (f32x4){0.f, 0.f, 0.f, 0.f};
                #pragma unroll
                for (int kt = 0; kt < 2; ++kt) {
                    bf16x8 bv[4];
                    #pragma unroll
                    for (int bt = 0; bt < 4; ++bt)
                        bv[bt] = *(const bf16x8*)&ybf[((bt * 2 + kt) * 64 + lane) * 8];
                    #pragma unroll
                    for (int oi = 0; oi < 2; ++oi)
                        #pragma unroll
                        for (int bt = 0; bt < 4; ++bt)
                            acc[oi][bt] = __builtin_amdgcn_mfma_f32_16x16x32_bf16(wg1[oi * 2 + kt], bv[bt], acc[oi][bt], 0, 0, 0);
                }
                // prefetch G2 kt=0..3 across the upcoming barrier
                #pragma unroll
                for (int kt = 0; kt < 4; ++kt)
                    #pragma unroll
                    for (int oi = 0; oi < 2; ++oi)
                        wg2a[kt * 2 + oi] = ldw(w1b + (long)((2 * w + oi) * 8 + kt) * 512 + lane * 8);
                // epilogue: relu + bias -> buf1 fragments
                // hidden h = (2w+oi)*16 + quad*4 + r -> kt1 = h/32 = w,
                // frag-lane = l16 + 16*(oi*2+qh), j = qp + r
                #pragma unroll
                for (int oi = 0; oi < 2; ++oi) {
                    f32x4 bias = *(const f32x4*)(b0 + (2 * w + oi) * 16 + quad * 4);
                    const int fl = ((oi * 2 + qh) * 16 + l16);
                    #pragma unroll
                    for (int bt = 0; bt < 4; ++bt) {
                        bf16x4 v;
                        #pragma unroll
                        for (int r = 0; r < 4; ++r)
                            v[r] = (__bf16)fmaxf(acc[oi][bt][r] + bias[r], 0.f);
                        *(bf16x4*)&buf1[((bt * 8 + w) * 64 + fl) * 8 + qp] = v;
                    }
                }
            }
            __syncthreads();  // B2: h0 ready

            bf16x8 wg3[8];    // G3 weights [kt]

            // ---- G2: W1 (A, kt<4 prefetched) x h0 (B, fragments) -> h1 frags
            {
                f32x4 acc[2][4];
                #pragma unroll
                for (int oi = 0; oi < 2; ++oi)
                    #pragma unroll
                    for (int bt = 0; bt < 4; ++bt)
                        acc[oi][bt] = (f32x4){0.f, 0.f, 0.f, 0.f};
                #pragma unroll
                for (int kt = 0; kt < 8; ++kt) {
                    bf16x8 aw[2];
                    #pragma unroll
                    for (int oi = 0; oi < 2; ++oi)
                        aw[oi] = (kt < 4) ? wg2a[kt * 2 + oi]
                                          : ldw(w1b + (long)((2 * w + oi) * 8 + kt) * 512 + lane * 8);
                    bf16x8 bv[4];
                    #pragma unroll
                    for (int bt = 0; bt < 4; ++bt)
                        bv[bt] = *(const bf16x8*)&buf1[((bt * 8 + kt) * 64 + lane) * 8];
                    #pragma unroll
                    for (int oi = 0; oi < 2; ++oi)
                        #pragma unroll
                        for (int bt = 0; bt < 4; ++bt)
                            acc[oi][bt] = __builtin_amdgcn_mfma_f32_16x16x32_bf16(aw[oi], bv[bt], acc[oi][bt], 0, 0, 0);
                }
                // epilogue: relu + bias -> buf2 fragments
                #pragma unroll
                for (int oi = 0; oi < 2; ++oi) {
                    f32x4 bias = *(const f32x4*)(b1 + (2 * w + oi) * 16 + quad * 4);
                    const int fl = ((oi * 2 + qh) * 16 + l16);
                    #pragma unroll
                    for (int bt = 0; bt < 4; ++bt) {
                        bf16x4 v;
                        #pragma unroll
                        for (int r = 0; r < 4; ++r)
                            v[r] = (__bf16)fmaxf(acc[oi][bt][r] + bias[r], 0.f);
                        *(bf16x4*)&buf2[((bt * 8 + w) * 64 + fl) * 8 + qp] = v;
                    }
                }
                // prefetch G3 weights across the upcoming barrier (wave pair
                // w, w^1 load the same otD tile — 2x W2 loads, negligible)
                #pragma unroll
                for (int kt = 0; kt < 8; ++kt)
                    wg3[kt] = ldw(w2b + (long)(otD * 8 + kt) * 512 + lane * 8);
            }
            __syncthreads();  // B3: h1 ready (also all buf1 reads done)

            // ---- G3: W2 (A, prefetched in wg3) x h1 (B, fragments) -> regs
            // wave owns (dim tile otD, batch half bh): bt in {bh*2, bh*2+1}
            {
                f32x4 acc3[2];
                #pragma unroll
                for (int bt = 0; bt < 2; ++bt)
                    acc3[bt] = (f32x4){0.f, 0.f, 0.f, 0.f};
                #pragma unroll
                for (int kt = 0; kt < 8; ++kt) {
                    #pragma unroll
                    for (int bt = 0; bt < 2; ++bt) {
                        bf16x8 bv = *(const bf16x8*)&buf2[(((bh * 2 + bt) * 8 + kt) * 64 + lane) * 8];
                        acc3[bt] = __builtin_amdgcn_mfma_f32_16x16x32_bf16(wg3[kt], bv, acc3[bt], 0, 0, 0);
                    }
                }
                // prefetch next G1 weights (low-pressure region)
                #pragma unroll
                for (int oi = 0; oi < 2; ++oi)
                    #pragma unroll
                    for (int kt = 0; kt < 2; ++kt)
                        wg1[oi * 2 + kt] = ldw(w0n + (long)((2 * w + oi) * 2 + kt) * 512 + lane * 8);
                f32x4 bias = *(const f32x4*)(b2 + otD * 16 + quad * 4);
                if (net == 0) {
                    #pragma unroll
                    for (int bt = 0; bt < 2; ++bt)
                        #pragma unroll
                        for (int r = 0; r < 4; ++r)
                            locr[bt][r] = acc3[bt][r] + bias[r];
                } else {
                    #pragma unroll
                    for (int bt = 0; bt < 2; ++bt)
                        #pragma unroll
                        for (int r = 0; r < 4; ++r)
                            scr[bt][r] = acc3[bt][r] + bias[r];
                }
            }
            // no barrier after G3: next G1 writes buf1 (reads drained at B3);
            // next G2's buf2 writes are behind the next B2
        }

        // coupling update, pure registers: y = exp(-sc) * (y - loc)
        #pragma unroll
        for (int bt = 0; bt < 2; ++bt)
            #pragma unroll
            for (int r = 0; r < 4; ++r)
                y[bt][r] = __expf(-scr[bt][r]) * (y[bt][r] - locr[bt][r]);
        // next ybf write safe: all ybf readers (both nets' G1) are behind this
        // layer's B2 barriers
    }

    #pragma unroll
    for (int bt = 0; bt < 2; ++bt)
        *(f32x4*)(out + (long)(blk * MTILE + bh * 32 + bt * 16 + l16) * DIM
                      + otD * 16 + quad * 4) = y[bt];
}

extern "C" void kernel_launch(void* const* d_in, const int* in_sizes, int n_in,
                              void* d_out, int out_size, void* d_ws, size_t ws_size,
                              hipStream_t stream) {
    const float* u   = (const float*)d_in[0];
    const float* lW0 = (const float*)d_in[1];
    const float* lb0 = (const float*)d_in[2];
    const float* lW1 = (const float*)d_in[3];
    const float* lb1 = (const float*)d_in[4];
    const float* lW2 = (const float*)d_in[5];
    const float* lb2 = (const float*)d_in[6];
    const float* sW0 = (const float*)d_in[7];
    const float* sb0 = (const float*)d_in[8];
    const float* sW1 = (const float*)d_in[9];
    const float* sb1 = (const float*)d_in[10];
    const float* sW2 = (const float*)d_in[11];
    const float* sb2 = (const float*)d_in[12];
    // d_in[13..15] = M0,M1,M2 — masks are computed analytically in pack_weights

    if (ws_size < (size_t)PACK_TOT * sizeof(__bf16)) return;
    __bf16* ws = (__bf16*)d_ws;

    pack_weights<<<PACK_TOT / 8 / 256, 256, 0, stream>>>(
        lW0, lW1, lW2, sW0, sW1, sW2, ws);
    flow_kernel<<<NBLOCKS, 512, 0, stream>>>(
        u, ws, lb0, lb1, lb2, sb0, sb1, sb2, (float*)d_out);
}